// Round 1
// baseline (379.262 us; speedup 1.0000x reference)
//
#include <hip/hip_runtime.h>
#include <hip/hip_bf16.h>
#include <stdint.h>

// ---------------------------------------------------------------------------
// att_layer: out = softmax((q@Wq+bq)(k@Wk+bk)^T * scale) @ (v@Wv+bv) @ Wo + bo
// N=16384, IN=256, HID=128, OUT=256, fp32 in/out, bf16 MFMA internally.
//
// Pipeline:
//   wt_kernel   : W[K][C] f32 -> WT[C][K] bf16 (x4 weights)
//   proj_kernel : qh (=SCALE*(q@Wq+bq)), kh, vhT (transposed) bf16
//   flash_kernel: KV-split flash attention, unnormalized O + (m,l) per split
//   combine     : merge splits -> O bf16 [N][128]
//   oproj       : out = O@Wo + bo  (f32 out)
// ---------------------------------------------------------------------------

#define N_TOK 16384
#define IN_DIM 256
#define HID 128
#define OUT_DIM 256
#define KVB 64

typedef __bf16  bf16x8 __attribute__((ext_vector_type(8)));
typedef short   short8 __attribute__((ext_vector_type(8)));
typedef float   f32x4  __attribute__((ext_vector_type(4)));

#define MFMA(a, b, c) __builtin_amdgcn_mfma_f32_16x16x32_bf16((a), (b), (c), 0, 0, 0)

__device__ __forceinline__ short f2bf(float f) {
    union { float f; uint32_t u; } v; v.f = f;
    uint32_t r = v.u + 0x7FFFu + ((v.u >> 16) & 1u);   // RNE
    return (short)(r >> 16);
}

// ------------------------- weight transpose ------------------------------
__global__ void wt_kernel(const float* __restrict__ W, short* __restrict__ WT,
                          int K, int C) {
    int idx = blockIdx.x * 256 + threadIdx.x;
    if (idx >= K * C) return;
    int k = idx / C, c = idx % C;
    WT[c * K + k] = f2bf(W[idx]);
}

// ------------------------- projection ------------------------------------
// Y = (X @ W + b) * post_scale ; X [N][256] f32, WT [128][256] bf16.
// transpose_out=0: Y[row][col] row-major [N][128]; =1: Y[col][row] [128][N].
__global__ __launch_bounds__(256) void proj_kernel(
    const float* __restrict__ X, const short* __restrict__ WT,
    const float* __restrict__ bias, short* __restrict__ Y,
    float post_scale, int transpose_out)
{
    const int lane = threadIdx.x & 63;
    const int wave = threadIdx.x >> 6;
    const int g = lane >> 4, c = lane & 15;
    const int rowbase = blockIdx.x * 64 + wave * 16;

    // A frags: row = rowbase + c, features kk*32 + 8g + j
    bf16x8 a[8];
    const float* xrow = X + (size_t)(rowbase + c) * IN_DIM;
#pragma unroll
    for (int kk = 0; kk < 8; ++kk) {
        const float* p = xrow + kk * 32 + 8 * g;
        float4 f0 = *(const float4*)(p);
        float4 f1 = *(const float4*)(p + 4);
        short8 t;
        t[0]=f2bf(f0.x); t[1]=f2bf(f0.y); t[2]=f2bf(f0.z); t[3]=f2bf(f0.w);
        t[4]=f2bf(f1.x); t[5]=f2bf(f1.y); t[6]=f2bf(f1.z); t[7]=f2bf(f1.w);
        a[kk] = __builtin_bit_cast(bf16x8, t);
    }

    f32x4 acc[8];
#pragma unroll
    for (int nf = 0; nf < 8; ++nf) acc[nf] = (f32x4){0.f, 0.f, 0.f, 0.f};

#pragma unroll
    for (int kk = 0; kk < 8; ++kk) {
#pragma unroll
        for (int nf = 0; nf < 8; ++nf) {
            bf16x8 b = *(const bf16x8*)(WT + (size_t)(c + 16 * nf) * IN_DIM + kk * 32 + 8 * g);
            acc[nf] = MFMA(a[kk], b, acc[nf]);
        }
    }

#pragma unroll
    for (int nf = 0; nf < 8; ++nf) {
        int col = c + 16 * nf;
        float bval = bias[col];
#pragma unroll
        for (int r = 0; r < 4; ++r) {
            int row = rowbase + 4 * g + r;
            short val = f2bf((acc[nf][r] + bval) * post_scale);
            if (transpose_out) Y[(size_t)col * N_TOK + row] = val;
            else               Y[(size_t)row * HID + col] = val;
        }
    }
}

// ------------------------- flash attention -------------------------------
// Block: 512 thr (8 waves), each wave owns 32 q-rows (BM=256).
// grid = (N/256, nsplit); split s covers keys [s*N/ns, (s+1)*N/ns).
// LDS: K [64key][128f] bf16 + V [128d][64key] bf16, double-buffered, both
// stored with XOR-chunk swizzle applied on the *global source* (m173) so
// ds_reads use chunk^(row&7) and stay ~conflict-free. P goes through a
// per-wave swizzled LDS buffer to reach the PV A-fragment layout.
__global__ __launch_bounds__(512, 2) void flash_kernel(
    const short* __restrict__ qh, const short* __restrict__ kh,
    const short* __restrict__ vhT,
    float* __restrict__ Opart, float* __restrict__ Mpart, float* __restrict__ Lpart,
    int nsplit)
{
    __shared__ short K_lds[2][KVB * HID];        // 2 x 16 KB
    __shared__ short V_lds[2][HID * KVB];        // 2 x 16 KB
    __shared__ short P_lds[8][32 * KVB];         // 8 x 4 KB

    const int lane = threadIdx.x & 63;
    const int wave = threadIdx.x >> 6;
    const int g = lane >> 4, c = lane & 15;
    const int split = blockIdx.y;
    const int qbase = blockIdx.x * 256 + wave * 32;
    const int kvlen = N_TOK / nsplit;
    const int kv0 = split * kvlen;
    const int ntiles = kvlen / KVB;

    // Q fragments hoisted (A: row = lane&15, k = kk*32+8g+j)
    bf16x8 aq[2][4];
#pragma unroll
    for (int m = 0; m < 2; ++m) {
        const short* qrow = qh + (size_t)(qbase + 16 * m + c) * HID;
#pragma unroll
        for (int kk = 0; kk < 4; ++kk)
            aq[m][kk] = *(const bf16x8*)(qrow + kk * 32 + 8 * g);
    }

    f32x4 o[2][8];
#pragma unroll
    for (int m = 0; m < 2; ++m)
#pragma unroll
        for (int nf = 0; nf < 8; ++nf) o[m][nf] = (f32x4){0.f, 0.f, 0.f, 0.f};
    float mrow[2][4], lrow[2][4];
#pragma unroll
    for (int m = 0; m < 2; ++m)
#pragma unroll
        for (int r = 0; r < 4; ++r) { mrow[m][r] = -1e30f; lrow[m][r] = 0.f; }

    // staging slots: each thread moves 2x16B for K and 2x16B for V per tile
    const uint32_t slot0 = (uint32_t)threadIdx.x * 16;
    const uint32_t slot1 = slot0 + 8192;

    auto ksrc = [&](int t, uint32_t L) -> const short* {
        uint32_t row = L >> 8, chunk = (L >> 4) & 15;
        uint32_t sc = chunk ^ (row & 7);
        return kh + (size_t)(kv0 + t * KVB + row) * HID + sc * 8;
    };
    auto vsrc = [&](int t, uint32_t L) -> const short* {
        uint32_t d = L >> 7, chunk = (L >> 4) & 7;
        uint32_t sc = chunk ^ (d & 7);
        return vhT + (size_t)d * N_TOK + (kv0 + t * KVB) + sc * 8;
    };

    { // prologue: stage tile 0 into buffer 0
        bf16x8 k0 = *(const bf16x8*)ksrc(0, slot0);
        bf16x8 k1 = *(const bf16x8*)ksrc(0, slot1);
        bf16x8 v0 = *(const bf16x8*)vsrc(0, slot0);
        bf16x8 v1 = *(const bf16x8*)vsrc(0, slot1);
        *(bf16x8*)&K_lds[0][slot0 >> 1] = k0;
        *(bf16x8*)&K_lds[0][slot1 >> 1] = k1;
        *(bf16x8*)&V_lds[0][slot0 >> 1] = v0;
        *(bf16x8*)&V_lds[0][slot1 >> 1] = v1;
    }
    __syncthreads();

    for (int t = 0; t < ntiles; ++t) {
        const int cur = t & 1;
        const short* Kc = &K_lds[cur][0];
        const short* Vc = &V_lds[cur][0];
        const bool pref = (t + 1 < ntiles);

        // issue next-tile global loads early; ds_write after compute (T14-lite)
        bf16x8 k0, k1, v0, v1;
        if (pref) {
            k0 = *(const bf16x8*)ksrc(t + 1, slot0);
            k1 = *(const bf16x8*)ksrc(t + 1, slot1);
            v0 = *(const bf16x8*)vsrc(t + 1, slot0);
            v1 = *(const bf16x8*)vsrc(t + 1, slot1);
        }

        // ---- QK^T : S[32 q][64 key] ----
        f32x4 s[2][4];
#pragma unroll
        for (int m = 0; m < 2; ++m)
#pragma unroll
            for (int nf = 0; nf < 4; ++nf) s[m][nf] = (f32x4){0.f, 0.f, 0.f, 0.f};
#pragma unroll
        for (int kk = 0; kk < 4; ++kk) {
#pragma unroll
            for (int nf = 0; nf < 4; ++nf) {
                const bf16x8 b = *(const bf16x8*)(Kc + (c + 16 * nf) * 128
                                    + (((4 * kk + g) ^ (c & 7)) << 3));
                s[0][nf] = MFMA(aq[0][kk], b, s[0][nf]);
                s[1][nf] = MFMA(aq[1][kk], b, s[1][nf]);
            }
        }

        // ---- online softmax (row = 16m + 4g + r lives on 16 c-lanes) ----
#pragma unroll
        for (int m = 0; m < 2; ++m) {
#pragma unroll
            for (int r = 0; r < 4; ++r) {
                float pm = fmaxf(fmaxf(s[m][0][r], s[m][1][r]),
                                 fmaxf(s[m][2][r], s[m][3][r]));
#pragma unroll
                for (int d = 1; d < 16; d <<= 1) pm = fmaxf(pm, __shfl_xor(pm, d));
                float mn = fmaxf(mrow[m][r], pm);
                float cf = __expf(mrow[m][r] - mn);
                mrow[m][r] = mn;
                float rs = 0.f;
#pragma unroll
                for (int nf = 0; nf < 4; ++nf) {
                    float pv = __expf(s[m][nf][r] - mn);
                    s[m][nf][r] = pv;               // reuse S regs for P
                    rs += pv;
                }
#pragma unroll
                for (int d = 1; d < 16; d <<= 1) rs += __shfl_xor(rs, d);
                lrow[m][r] = lrow[m][r] * cf + rs;
#pragma unroll
                for (int nf = 0; nf < 8; ++nf) o[m][nf][r] *= cf;
            }
        }

        // ---- P -> LDS (swizzled [32 row][64 key] bf16, per-wave) ----
        short* Pw = &P_lds[wave][0];
#pragma unroll
        for (int m = 0; m < 2; ++m)
#pragma unroll
            for (int r = 0; r < 4; ++r) {
                int row = 16 * m + 4 * g + r;
#pragma unroll
                for (int nf = 0; nf < 4; ++nf) {
                    int ch = ((c >> 3) + 2 * nf) ^ (row & 7);
                    Pw[row * 64 + ch * 8 + (c & 7)] = f2bf(s[m][nf][r]);
                }
            }

        // ---- PV : O += P[32q][64k] @ V[64k][128d] ----
#pragma unroll
        for (int kk = 0; kk < 2; ++kk) {
            bf16x8 pa[2];
#pragma unroll
            for (int m = 0; m < 2; ++m) {
                int row = c + 16 * m;   // A-row = lane&15
                pa[m] = *(const bf16x8*)(Pw + row * 64 + (((4 * kk + g) ^ (c & 7)) << 3));
            }
#pragma unroll
            for (int nf = 0; nf < 8; ++nf) {
                const bf16x8 bfrag = *(const bf16x8*)(Vc + (c + 16 * nf) * 64
                                        + (((4 * kk + g) ^ (c & 7)) << 3));
                o[0][nf] = MFMA(pa[0], bfrag, o[0][nf]);
                o[1][nf] = MFMA(pa[1], bfrag, o[1][nf]);
            }
        }

        if (pref) {
            *(bf16x8*)&K_lds[cur ^ 1][slot0 >> 1] = k0;
            *(bf16x8*)&K_lds[cur ^ 1][slot1 >> 1] = k1;
            *(bf16x8*)&V_lds[cur ^ 1][slot0 >> 1] = v0;
            *(bf16x8*)&V_lds[cur ^ 1][slot1 >> 1] = v1;
            __syncthreads();
        }
    }

    // ---- epilogue: unnormalized O + (m, l) per split ----
    const size_t obase = ((size_t)split * N_TOK + qbase) * HID;
#pragma unroll
    for (int m = 0; m < 2; ++m)
#pragma unroll
        for (int nf = 0; nf < 8; ++nf) {
            int col = c + 16 * nf;
#pragma unroll
            for (int r = 0; r < 4; ++r) {
                int row = 16 * m + 4 * g + r;
                Opart[obase + (size_t)row * HID + col] = o[m][nf][r];
            }
        }
    if (c == 0) {
#pragma unroll
        for (int m = 0; m < 2; ++m)
#pragma unroll
            for (int r = 0; r < 4; ++r) {
                int row = 16 * m + 4 * g + r;
                Mpart[(size_t)split * N_TOK + qbase + row] = mrow[m][r];
                Lpart[(size_t)split * N_TOK + qbase + row] = lrow[m][r];
            }
    }
}

// ------------------------- split combine ---------------------------------
__global__ void combine_kernel(const float* __restrict__ Opart,
                               const float* __restrict__ Mpart,
                               const float* __restrict__ Lpart,
                               short* __restrict__ O, int nsplit)
{
    int idx = blockIdx.x * 256 + threadIdx.x;
    int row = idx >> 5;
    int d4 = (idx & 31) << 2;
    if (row >= N_TOK) return;
    float M = -1e30f;
    for (int s = 0; s < nsplit; ++s) M = fmaxf(M, Mpart[(size_t)s * N_TOK + row]);
    float denom = 0.f, a0 = 0.f, a1 = 0.f, a2 = 0.f, a3 = 0.f;
    for (int s = 0; s < nsplit; ++s) {
        float w = __expf(Mpart[(size_t)s * N_TOK + row] - M);
        denom += w * Lpart[(size_t)s * N_TOK + row];
        float4 vv = *(const float4*)(Opart + ((size_t)s * N_TOK + row) * HID + d4);
        a0 += w * vv.x; a1 += w * vv.y; a2 += w * vv.z; a3 += w * vv.w;
    }
    float inv = 1.0f / denom;
    short4 ov;
    ov.x = f2bf(a0 * inv); ov.y = f2bf(a1 * inv);
    ov.z = f2bf(a2 * inv); ov.w = f2bf(a3 * inv);
    *(short4*)(O + (size_t)row * HID + d4) = ov;
}

// ------------------------- output projection -----------------------------
__global__ __launch_bounds__(256) void oproj_kernel(
    const short* __restrict__ O, const short* __restrict__ WoT,
    const float* __restrict__ bo, float* __restrict__ out)
{
    const int lane = threadIdx.x & 63;
    const int wave = threadIdx.x >> 6;
    const int g = lane >> 4, c = lane & 15;
    const int rowbase = blockIdx.x * 64 + wave * 16;

    bf16x8 a[4];
    const short* orow = O + (size_t)(rowbase + c) * HID;
#pragma unroll
    for (int kk = 0; kk < 4; ++kk)
        a[kk] = *(const bf16x8*)(orow + kk * 32 + 8 * g);

    f32x4 acc[16];
#pragma unroll
    for (int nf = 0; nf < 16; ++nf) acc[nf] = (f32x4){0.f, 0.f, 0.f, 0.f};

#pragma unroll
    for (int kk = 0; kk < 4; ++kk)
#pragma unroll
        for (int nf = 0; nf < 16; ++nf) {
            bf16x8 b = *(const bf16x8*)(WoT + (size_t)(c + 16 * nf) * HID + kk * 32 + 8 * g);
            acc[nf] = MFMA(a[kk], b, acc[nf]);
        }

#pragma unroll
    for (int nf = 0; nf < 16; ++nf) {
        int col = c + 16 * nf;
        float bval = bo[col];
#pragma unroll
        for (int r = 0; r < 4; ++r)
            out[(size_t)(rowbase + 4 * g + r) * OUT_DIM + col] = acc[nf][r] + bval;
    }
}

// ------------------------- launch ----------------------------------------
extern "C" void kernel_launch(void* const* d_in, const int* in_sizes, int n_in,
                              void* d_out, int out_size, void* d_ws, size_t ws_size,
                              hipStream_t stream)
{
    (void)in_sizes; (void)n_in; (void)out_size;
    const float* q  = (const float*)d_in[0];
    const float* k  = (const float*)d_in[1];
    const float* v  = (const float*)d_in[2];
    const float* Wq = (const float*)d_in[3];
    const float* bq = (const float*)d_in[4];
    const float* Wk = (const float*)d_in[5];
    const float* bk = (const float*)d_in[6];
    const float* Wv = (const float*)d_in[7];
    const float* bvp= (const float*)d_in[8];
    const float* Wo = (const float*)d_in[9];
    const float* bo = (const float*)d_in[10];
    float* out = (float*)d_out;

    auto need = [](int ns) -> size_t {
        return (size_t)(4 * 64 * 1024)
             + (size_t)4 * N_TOK * HID * 2
             + (size_t)ns * N_TOK * HID * 4
             + (size_t)ns * N_TOK * 8
             + (size_t)64 * 1024;
    };
    int nsplit = 4;
    if (ws_size < need(4)) nsplit = 2;
    if (ws_size < need(2)) nsplit = 1;

    char* base = (char*)d_ws;
    size_t off = 0;
    auto alloc = [&](size_t bytes) -> void* {
        void* p = base + off;
        off = (off + bytes + 255) & ~(size_t)255;
        return p;
    };
    short* wtq = (short*)alloc(128 * 256 * 2);
    short* wtk = (short*)alloc(128 * 256 * 2);
    short* wtv = (short*)alloc(128 * 256 * 2);
    short* wto = (short*)alloc(256 * 128 * 2);
    short* qh  = (short*)alloc((size_t)N_TOK * HID * 2);
    short* khb = (short*)alloc((size_t)N_TOK * HID * 2);
    short* vhT = (short*)alloc((size_t)N_TOK * HID * 2);
    short* Ob  = (short*)alloc((size_t)N_TOK * HID * 2);
    float* Opart = (float*)alloc((size_t)nsplit * N_TOK * HID * 4);
    float* Mp  = (float*)alloc((size_t)nsplit * N_TOK * 4);
    float* Lp  = (float*)alloc((size_t)nsplit * N_TOK * 4);

    const float SCALE = 0.088388347648318447f;  // 128^-0.5

    wt_kernel<<<128, 256, 0, stream>>>(Wq, wtq, 256, 128);
    wt_kernel<<<128, 256, 0, stream>>>(Wk, wtk, 256, 128);
    wt_kernel<<<128, 256, 0, stream>>>(Wv, wtv, 256, 128);
    wt_kernel<<<128, 256, 0, stream>>>(Wo, wto, 128, 256);

    proj_kernel<<<N_TOK / 64, 256, 0, stream>>>(q, wtq, bq, qh, SCALE, 0);
    proj_kernel<<<N_TOK / 64, 256, 0, stream>>>(k, wtk, bk, khb, 1.0f, 0);
    proj_kernel<<<N_TOK / 64, 256, 0, stream>>>(v, wtv, bvp, vhT, 1.0f, 1);

    flash_kernel<<<dim3(N_TOK / 256, nsplit), 512, 0, stream>>>(
        qh, khb, vhT, Opart, Mp, Lp, nsplit);

    combine_kernel<<<(N_TOK * 32) / 256, 256, 0, stream>>>(Opart, Mp, Lp, Ob, nsplit);

    oproj_kernel<<<N_TOK / 64, 256, 0, stream>>>(Ob, wto, bo, out);
}

// Round 2
// 287.713 us; speedup vs baseline: 1.3182x; 1.3182x over previous
//
#include <hip/hip_runtime.h>
#include <hip/hip_bf16.h>
#include <stdint.h>

// ---------------------------------------------------------------------------
// att_layer: out = softmax((q@Wq+bq)(k@Wk+bk)^T * scale) @ (v@Wv+bv) @ Wo + bo
// N=16384, IN=256, HID=128, OUT=256, fp32 in/out, bf16 MFMA internally.
//
// flash kernel v2: swapped QK^T (S^T via mfma(K,Q)) -> in-register softmax in
// exp2 domain (log2e folded into q-projection scale), defer-max rescale (T13),
// packed P via v_cvt_pk_bf16_f32 + swizzled ds_write_b64, PV as O^T = V^T P^T,
// K/V staged with global_load_lds (pre-swizzled global source, m173),
// BM=128 / KVB=32 / 256 threads, LDS 40KB -> 3 blocks/CU.
// ---------------------------------------------------------------------------

#define N_TOK 16384
#define IN_DIM 256
#define HID 128
#define OUT_DIM 256
#define KVB 32
#define BM 128

typedef __bf16  bf16x8 __attribute__((ext_vector_type(8)));
typedef short   short8 __attribute__((ext_vector_type(8)));
typedef float   f32x4  __attribute__((ext_vector_type(4)));

#define MFMA(a, b, c) __builtin_amdgcn_mfma_f32_16x16x32_bf16((a), (b), (c), 0, 0, 0)
#define EXP2(x) __builtin_amdgcn_exp2f(x)

__device__ __forceinline__ short f2bf(float f) {
    union { float f; uint32_t u; } v; v.f = f;
    uint32_t r = v.u + 0x7FFFu + ((v.u >> 16) & 1u);   // RNE
    return (short)(r >> 16);
}

__device__ __forceinline__ void gl16(const void* g, const void* l) {
    __builtin_amdgcn_global_load_lds(
        (const __attribute__((address_space(1))) void*)g,
        (__attribute__((address_space(3))) void*)l, 16, 0, 0);
}

// ------------------------- weight transpose ------------------------------
__global__ void wt_kernel(const float* __restrict__ W, short* __restrict__ WT,
                          int K, int C) {
    int idx = blockIdx.x * 256 + threadIdx.x;
    if (idx >= K * C) return;
    int k = idx / C, c = idx % C;
    WT[c * K + k] = f2bf(W[idx]);
}

// ------------------------- projection ------------------------------------
__global__ __launch_bounds__(256) void proj_kernel(
    const float* __restrict__ X, const short* __restrict__ WT,
    const float* __restrict__ bias, short* __restrict__ Y,
    float post_scale, int transpose_out)
{
    const int lane = threadIdx.x & 63;
    const int wave = threadIdx.x >> 6;
    const int g = lane >> 4, c = lane & 15;
    const int rowbase = blockIdx.x * 64 + wave * 16;

    bf16x8 a[8];
    const float* xrow = X + (size_t)(rowbase + c) * IN_DIM;
#pragma unroll
    for (int kk = 0; kk < 8; ++kk) {
        const float* p = xrow + kk * 32 + 8 * g;
        float4 f0 = *(const float4*)(p);
        float4 f1 = *(const float4*)(p + 4);
        short8 t;
        t[0]=f2bf(f0.x); t[1]=f2bf(f0.y); t[2]=f2bf(f0.z); t[3]=f2bf(f0.w);
        t[4]=f2bf(f1.x); t[5]=f2bf(f1.y); t[6]=f2bf(f1.z); t[7]=f2bf(f1.w);
        a[kk] = __builtin_bit_cast(bf16x8, t);
    }

    f32x4 acc[8];
#pragma unroll
    for (int nf = 0; nf < 8; ++nf) acc[nf] = (f32x4){0.f, 0.f, 0.f, 0.f};

#pragma unroll
    for (int kk = 0; kk < 8; ++kk) {
#pragma unroll
        for (int nf = 0; nf < 8; ++nf) {
            bf16x8 b = *(const bf16x8*)(WT + (size_t)(c + 16 * nf) * IN_DIM + kk * 32 + 8 * g);
            acc[nf] = MFMA(a[kk], b, acc[nf]);
        }
    }

#pragma unroll
    for (int nf = 0; nf < 8; ++nf) {
        int col = c + 16 * nf;
        float bval = bias[col];
#pragma unroll
        for (int r = 0; r < 4; ++r) {
            int row = rowbase + 4 * g + r;
            short val = f2bf((acc[nf][r] + bval) * post_scale);
            if (transpose_out) Y[(size_t)col * N_TOK + row] = val;
            else               Y[(size_t)row * HID + col] = val;
        }
    }
}

// ------------------------- flash attention v2 ----------------------------
// Block: 256 thr (4 waves), each wave owns 32 q-rows (BM=128).
// grid = (N/BM, nsplit). Logits in log2-domain (log2e folded into qh scale).
__global__ __launch_bounds__(256, 3) void flash_kernel(
    const short* __restrict__ qh, const short* __restrict__ kh,
    const short* __restrict__ vhT,
    float* __restrict__ Opart, float* __restrict__ Mpart, float* __restrict__ Lpart,
    int nsplit)
{
    __shared__ short K_lds[2][KVB * HID];   // 2 x 8 KB  [key][d] chunk-swizzled
    __shared__ short V_lds[2][HID * KVB];   // 2 x 8 KB  [d][key] chunk-swizzled
    __shared__ short P_lds[4][32 * KVB];    // 4 x 2 KB  per-wave [q][key] quad-swizzled

    const int tid  = threadIdx.x;
    const int lane = tid & 63;
    const int wave = tid >> 6;
    const int g = lane >> 4, c = lane & 15;
    const int split = blockIdx.y;
    const int qbase = blockIdx.x * BM + wave * 32;
    const int kvlen = N_TOK / nsplit;
    const int kv0 = split * kvlen;
    const int ntiles = kvlen / KVB;

    // Q B-fragments hoisted: aq[m][kk] = qh[q = qbase+16m+c][d = 32kk+8g+j]
    bf16x8 aq[2][4];
#pragma unroll
    for (int m = 0; m < 2; ++m) {
        const short* qrow = qh + (size_t)(qbase + 16 * m + c) * HID;
#pragma unroll
        for (int kk = 0; kk < 4; ++kk)
            aq[m][kk] = *(const bf16x8*)(qrow + kk * 32 + 8 * g);
    }

    f32x4 o[2][8];
#pragma unroll
    for (int m = 0; m < 2; ++m)
#pragma unroll
        for (int nf = 0; nf < 8; ++nf) o[m][nf] = (f32x4){0.f, 0.f, 0.f, 0.f};
    float mrow[2] = {-1e30f, -1e30f};   // per q-row (q = c+16m), log2 domain
    float lrow[2] = {0.f, 0.f};

    // --- staging source addresses (pre-swizzled global, m173) ---
    // K: LDS byte L (issue i: L = i*4096 + tid*16): row=L>>8, chunk16=(L>>4)&15,
    //    src chunk = chunk16 ^ (row&7).
    uint32_t Lk0 = (uint32_t)tid * 16;
    uint32_t Lk1 = 4096u + (uint32_t)tid * 16;
    uint32_t rk0 = Lk0 >> 8, ck0 = ((Lk0 >> 4) & 15) ^ (rk0 & 7);
    uint32_t rk1 = Lk1 >> 8, ck1 = ((Lk1 >> 4) & 15) ^ (rk1 & 7);
    const short* ksrc0 = kh + (size_t)(kv0 + rk0) * HID + ck0 * 8;
    const short* ksrc1 = kh + (size_t)(kv0 + rk1) * HID + ck1 * 8;
    // V: row d = L>>6, chunk = (L>>4)&3, src chunk = chunk ^ (d&3).
    uint32_t dv0 = Lk0 >> 6, cv0 = ((Lk0 >> 4) & 3) ^ (dv0 & 3);
    uint32_t dv1 = Lk1 >> 6, cv1 = ((Lk1 >> 4) & 3) ^ (dv1 & 3);
    const short* vsrc0 = vhT + (size_t)dv0 * N_TOK + kv0 + cv0 * 8;
    const short* vsrc1 = vhT + (size_t)dv1 * N_TOK + kv0 + cv1 * 8;

    auto stage = [&](int t, int buf) {
        gl16(ksrc0 + (size_t)t * (KVB * HID), &K_lds[buf][wave * 512]);
        gl16(ksrc1 + (size_t)t * (KVB * HID), &K_lds[buf][2048 + wave * 512]);
        gl16(vsrc0 + t * KVB, &V_lds[buf][wave * 512]);
        gl16(vsrc1 + t * KVB, &V_lds[buf][2048 + wave * 512]);
    };

    stage(0, 0);
    __syncthreads();

    short* Pw = &P_lds[wave][0];

    for (int t = 0; t < ntiles; ++t) {
        const int cur = t & 1;
        if (t + 1 < ntiles) stage(t + 1, cur ^ 1);
        const short* Kc = &K_lds[cur][0];
        const short* Vc = &V_lds[cur][0];

        // ---- QK^T swapped: s[m][nf][r] = S[q=c+16m][key=16nf+4g+r] ----
        f32x4 s[2][2];
#pragma unroll
        for (int m = 0; m < 2; ++m)
#pragma unroll
            for (int nf = 0; nf < 2; ++nf) s[m][nf] = (f32x4){0.f, 0.f, 0.f, 0.f};
#pragma unroll
        for (int kk = 0; kk < 4; ++kk) {
#pragma unroll
            for (int nf = 0; nf < 2; ++nf) {
                bf16x8 kf = *(const bf16x8*)(Kc + (16 * nf + c) * HID
                                + (((4 * kk + g) ^ (c & 7)) << 3));
                s[0][nf] = MFMA(kf, aq[0][kk], s[0][nf]);
                s[1][nf] = MFMA(kf, aq[1][kk], s[1][nf]);
            }
        }

        // ---- in-register online softmax (log2 domain), defer-max T13 ----
#pragma unroll
        for (int m = 0; m < 2; ++m) {
            float pm = fmaxf(fmaxf(fmaxf(s[m][0][0], s[m][0][1]),
                                   fmaxf(s[m][0][2], s[m][0][3])),
                             fmaxf(fmaxf(s[m][1][0], s[m][1][1]),
                                   fmaxf(s[m][1][2], s[m][1][3])));
            pm = fmaxf(pm, __shfl_xor(pm, 16));
            pm = fmaxf(pm, __shfl_xor(pm, 32));
            if (!__all(pm - mrow[m] <= 11.0f)) {       // rescale path
                float mn = fmaxf(mrow[m], pm);
                float cf = EXP2(mrow[m] - mn);
                lrow[m] *= cf;
#pragma unroll
                for (int nf = 0; nf < 8; ++nf)
#pragma unroll
                    for (int r = 0; r < 4; ++r) o[m][nf][r] *= cf;
                mrow[m] = mn;
            }
            float rs = 0.f;
#pragma unroll
            for (int nf = 0; nf < 2; ++nf)
#pragma unroll
                for (int r = 0; r < 4; ++r) {
                    float pv = EXP2(s[m][nf][r] - mrow[m]);
                    s[m][nf][r] = pv;
                    rs += pv;
                }
            rs += __shfl_xor(rs, 16);
            rs += __shfl_xor(rs, 32);
            lrow[m] += rs;
        }

        // ---- pack P (bf16) -> per-wave LDS, quad-swizzled ----
        // value s[m][nf][r] is P[q=c+16m][key=16nf+4g+r]; quad=4nf+g;
        // store at shorts: q*32 + (quad ^ (2*(c&3)))*4
#pragma unroll
        for (int m = 0; m < 2; ++m)
#pragma unroll
            for (int nf = 0; nf < 2; ++nf) {
                uint32_t q0, q1;
                asm("v_cvt_pk_bf16_f32 %0, %1, %2"
                    : "=v"(q0) : "v"(s[m][nf][0]), "v"(s[m][nf][1]));
                asm("v_cvt_pk_bf16_f32 %0, %1, %2"
                    : "=v"(q1) : "v"(s[m][nf][2]), "v"(s[m][nf][3]));
                int sq = (4 * nf + g) ^ (2 * (c & 3));
                uint2 qd; qd.x = q0; qd.y = q1;
                *(uint2*)(Pw + (c + 16 * m) * 32 + sq * 4) = qd;
            }
        asm volatile("" ::: "memory");   // order P writes before P reads

        // ---- PV: O^T[d][q] = V^T[d][key] @ P^T[key][q] ----
        bf16x8 pb[2];
#pragma unroll
        for (int m = 0; m < 2; ++m) {
            int sq0 = (2 * g) ^ (2 * (c & 3));
            pb[m] = *(const bf16x8*)(Pw + (c + 16 * m) * 32 + sq0 * 4);
        }
#pragma unroll
        for (int nf = 0; nf < 8; ++nf) {
            bf16x8 vf = *(const bf16x8*)(Vc + (16 * nf + c) * KVB
                            + ((g ^ (c & 3)) << 3));
            o[0][nf] = MFMA(vf, pb[0], o[0][nf]);
            o[1][nf] = MFMA(vf, pb[1], o[1][nf]);
        }

        __syncthreads();   // drains gload_lds (vmcnt) + all waves done with cur
    }

    // ---- epilogue: unnormalized O (float4 stores) + (m, l) per split ----
    const size_t obase = ((size_t)split * N_TOK + qbase) * HID;
#pragma unroll
    for (int m = 0; m < 2; ++m)
#pragma unroll
        for (int nf = 0; nf < 8; ++nf) {
            float4 vv; vv.x = o[m][nf][0]; vv.y = o[m][nf][1];
            vv.z = o[m][nf][2]; vv.w = o[m][nf][3];
            *(float4*)(Opart + obase + (size_t)(c + 16 * m) * HID + 16 * nf + 4 * g) = vv;
        }
    if (g == 0) {
#pragma unroll
        for (int m = 0; m < 2; ++m) {
            Mpart[(size_t)split * N_TOK + qbase + c + 16 * m] = mrow[m];
            Lpart[(size_t)split * N_TOK + qbase + c + 16 * m] = lrow[m];
        }
    }
}

// ------------------------- split combine ---------------------------------
__global__ void combine_kernel(const float* __restrict__ Opart,
                               const float* __restrict__ Mpart,
                               const float* __restrict__ Lpart,
                               short* __restrict__ O, int nsplit)
{
    int idx = blockIdx.x * 256 + threadIdx.x;
    int row = idx >> 5;
    int d4 = (idx & 31) << 2;
    if (row >= N_TOK) return;
    float M = -1e30f;
    for (int s = 0; s < nsplit; ++s) M = fmaxf(M, Mpart[(size_t)s * N_TOK + row]);
    float denom = 0.f, a0 = 0.f, a1 = 0.f, a2 = 0.f, a3 = 0.f;
    for (int s = 0; s < nsplit; ++s) {
        float w = EXP2(Mpart[(size_t)s * N_TOK + row] - M);   // log2 domain
        denom += w * Lpart[(size_t)s * N_TOK + row];
        float4 vv = *(const float4*)(Opart + ((size_t)s * N_TOK + row) * HID + d4);
        a0 += w * vv.x; a1 += w * vv.y; a2 += w * vv.z; a3 += w * vv.w;
    }
    float inv = 1.0f / denom;
    short4 ov;
    ov.x = f2bf(a0 * inv); ov.y = f2bf(a1 * inv);
    ov.z = f2bf(a2 * inv); ov.w = f2bf(a3 * inv);
    *(short4*)(O + (size_t)row * HID + d4) = ov;
}

// ------------------------- output projection -----------------------------
__global__ __launch_bounds__(256) void oproj_kernel(
    const short* __restrict__ O, const short* __restrict__ WoT,
    const float* __restrict__ bo, float* __restrict__ out)
{
    const int lane = threadIdx.x & 63;
    const int wave = threadIdx.x >> 6;
    const int g = lane >> 4, c = lane & 15;
    const int rowbase = blockIdx.x * 64 + wave * 16;

    bf16x8 a[4];
    const short* orow = O + (size_t)(rowbase + c) * HID;
#pragma unroll
    for (int kk = 0; kk < 4; ++kk)
        a[kk] = *(const bf16x8*)(orow + kk * 32 + 8 * g);

    f32x4 acc[16];
#pragma unroll
    for (int nf = 0; nf < 16; ++nf) acc[nf] = (f32x4){0.f, 0.f, 0.f, 0.f};

#pragma unroll
    for (int kk = 0; kk < 4; ++kk)
#pragma unroll
        for (int nf = 0; nf < 16; ++nf) {
            bf16x8 b = *(const bf16x8*)(WoT + (size_t)(c + 16 * nf) * HID + kk * 32 + 8 * g);
            acc[nf] = MFMA(a[kk], b, acc[nf]);
        }

#pragma unroll
    for (int nf = 0; nf < 16; ++nf) {
        int col = c + 16 * nf;
        float bval = bo[col];
#pragma unroll
        for (int r = 0; r < 4; ++r)
            out[(size_t)(rowbase + 4 * g + r) * OUT_DIM + col] = acc[nf][r] + bval;
    }
}

// ------------------------- launch ----------------------------------------
extern "C" void kernel_launch(void* const* d_in, const int* in_sizes, int n_in,
                              void* d_out, int out_size, void* d_ws, size_t ws_size,
                              hipStream_t stream)
{
    (void)in_sizes; (void)n_in; (void)out_size;
    const float* q  = (const float*)d_in[0];
    const float* k  = (const float*)d_in[1];
    const float* v  = (const float*)d_in[2];
    const float* Wq = (const float*)d_in[3];
    const float* bq = (const float*)d_in[4];
    const float* Wk = (const float*)d_in[5];
    const float* bk = (const float*)d_in[6];
    const float* Wv = (const float*)d_in[7];
    const float* bvp= (const float*)d_in[8];
    const float* Wo = (const float*)d_in[9];
    const float* bo = (const float*)d_in[10];
    float* out = (float*)d_out;

    auto need = [](int ns) -> size_t {
        return (size_t)(512 * 1024)
             + (size_t)4 * N_TOK * HID * 2
             + (size_t)ns * N_TOK * HID * 4
             + (size_t)ns * N_TOK * 8
             + (size_t)256 * 1024;
    };
    int nsplit = 8;
    if (ws_size < need(8)) nsplit = 4;
    if (ws_size < need(4)) nsplit = 2;
    if (ws_size < need(2)) nsplit = 1;

    char* base = (char*)d_ws;
    size_t off = 0;
    auto alloc = [&](size_t bytes) -> void* {
        void* p = base + off;
        off = (off + bytes + 255) & ~(size_t)255;
        return p;
    };
    short* wtq = (short*)alloc(128 * 256 * 2);
    short* wtk = (short*)alloc(128 * 256 * 2);
    short* wtv = (short*)alloc(128 * 256 * 2);
    short* wto = (short*)alloc(256 * 128 * 2);
    short* qh  = (short*)alloc((size_t)N_TOK * HID * 2);
    short* khb = (short*)alloc((size_t)N_TOK * HID * 2);
    short* vhT = (short*)alloc((size_t)N_TOK * HID * 2);
    short* Ob  = (short*)alloc((size_t)N_TOK * HID * 2);
    float* Opart = (float*)alloc((size_t)nsplit * N_TOK * HID * 4);
    float* Mp  = (float*)alloc((size_t)nsplit * N_TOK * 4);
    float* Lp  = (float*)alloc((size_t)nsplit * N_TOK * 4);

    // 128^-0.5 * log2(e): logits land in log2 domain for exp2-based softmax
    const float SCALE_L2E = 0.088388347648318447f * 1.4426950408889634f;

    wt_kernel<<<128, 256, 0, stream>>>(Wq, wtq, 256, 128);
    wt_kernel<<<128, 256, 0, stream>>>(Wk, wtk, 256, 128);
    wt_kernel<<<128, 256, 0, stream>>>(Wv, wtv, 256, 128);
    wt_kernel<<<128, 256, 0, stream>>>(Wo, wto, 128, 256);

    proj_kernel<<<N_TOK / 64, 256, 0, stream>>>(q, wtq, bq, qh, SCALE_L2E, 0);
    proj_kernel<<<N_TOK / 64, 256, 0, stream>>>(k, wtk, bk, khb, 1.0f, 0);
    proj_kernel<<<N_TOK / 64, 256, 0, stream>>>(v, wtv, bvp, vhT, 1.0f, 1);

    flash_kernel<<<dim3(N_TOK / BM, nsplit), 256, 0, stream>>>(
        qh, khb, vhT, Opart, Mp, Lp, nsplit);

    combine_kernel<<<(N_TOK * 32) / 256, 256, 0, stream>>>(Opart, Mp, Lp, Ob, nsplit);

    oproj_kernel<<<N_TOK / 64, 256, 0, stream>>>(Ob, wto, bo, out);
}

// Round 4
// 234.811 us; speedup vs baseline: 1.6152x; 1.2253x over previous
//
#include <hip/hip_runtime.h>
#include <hip/hip_bf16.h>
#include <stdint.h>

// ---------------------------------------------------------------------------
// att_layer: out = softmax((q@Wq+bq)(k@Wk+bk)^T * scale) @ (v@Wv+bv) @ Wo + bo
// N=16384, IN=256, HID=128, OUT=256, fp32 in/out, bf16 MFMA internally.
//
// flash v4 = v3 with all v_permlane32_swap_b32 replaced by __shfl_xor(.,32)
// (alias-proof + direction-unambiguous cross-half exchange).
//   - swapped QK^T via mfma_f32_32x32x16_bf16: lane owns q-col, 32/64 scores
//   - in-register softmax (log2 domain), defer-max THR=11
//   - P -> PV A-frags in-register: cvt_pk + shfl_xor(32) + per-half select
//   - K [64][128] + V^T [128][64] LDS, double-buffered, chunk-XOR swizzle,
//     staged with global_load_lds width-16 from pre-swizzled global source
// ---------------------------------------------------------------------------

#define N_TOK 16384
#define IN_DIM 256
#define HID 128
#define OUT_DIM 256
#define KVB 64
#define BM 256

typedef __bf16   bf16x8 __attribute__((ext_vector_type(8)));
typedef short    short8 __attribute__((ext_vector_type(8)));
typedef float    f32x4  __attribute__((ext_vector_type(4)));
typedef float    f32x16 __attribute__((ext_vector_type(16)));
typedef uint32_t u32x4  __attribute__((ext_vector_type(4)));

#define MFMA16(a,b,c) __builtin_amdgcn_mfma_f32_16x16x32_bf16((a),(b),(c),0,0,0)
#define MFMA32(a,b,c) __builtin_amdgcn_mfma_f32_32x32x16_bf16((a),(b),(c),0,0,0)
#define EXP2(x) __builtin_amdgcn_exp2f(x)

__device__ __forceinline__ short f2bf(float f) {
    union { float f; uint32_t u; } v; v.f = f;
    uint32_t r = v.u + 0x7FFFu + ((v.u >> 16) & 1u);   // RNE
    return (short)(r >> 16);
}

__device__ __forceinline__ uint32_t cvtpk(float lo, float hi) {
    uint32_t d;
    asm("v_cvt_pk_bf16_f32 %0, %1, %2" : "=v"(d) : "v"(lo), "v"(hi));
    return d;
}

// cross-half exchange: lane l <-> lane l^32 (unambiguous, alias-proof)
__device__ __forceinline__ uint32_t xswap(uint32_t x) {
    return (uint32_t)__shfl_xor((int)x, 32, 64);
}

__device__ __forceinline__ void gl16(const void* g, const void* l) {
    __builtin_amdgcn_global_load_lds(
        (const __attribute__((address_space(1))) void*)g,
        (__attribute__((address_space(3))) void*)l, 16, 0, 0);
}

__device__ __forceinline__ float vmax16(f32x16 v) {
    float a = fmaxf(fmaxf(v[0], v[1]),  fmaxf(v[2], v[3]));
    float b = fmaxf(fmaxf(v[4], v[5]),  fmaxf(v[6], v[7]));
    float c = fmaxf(fmaxf(v[8], v[9]),  fmaxf(v[10], v[11]));
    float d = fmaxf(fmaxf(v[12], v[13]), fmaxf(v[14], v[15]));
    return fmaxf(fmaxf(a, b), fmaxf(c, d));
}

// ------------------------- weight transpose ------------------------------
__global__ void wt_kernel(const float* __restrict__ W, short* __restrict__ WT,
                          int K, int C) {
    int idx = blockIdx.x * 256 + threadIdx.x;
    if (idx >= K * C) return;
    int k = idx / C, c = idx % C;
    WT[c * K + k] = f2bf(W[idx]);
}

// ------------------------- projection ------------------------------------
__global__ __launch_bounds__(256) void proj_kernel(
    const float* __restrict__ X, const short* __restrict__ WT,
    const float* __restrict__ bias, short* __restrict__ Y,
    float post_scale, int transpose_out)
{
    const int lane = threadIdx.x & 63;
    const int wave = threadIdx.x >> 6;
    const int g = lane >> 4, c = lane & 15;
    const int rowbase = blockIdx.x * 64 + wave * 16;

    bf16x8 a[8];
    const float* xrow = X + (size_t)(rowbase + c) * IN_DIM;
#pragma unroll
    for (int kk = 0; kk < 8; ++kk) {
        const float* p = xrow + kk * 32 + 8 * g;
        float4 f0 = *(const float4*)(p);
        float4 f1 = *(const float4*)(p + 4);
        short8 t;
        t[0]=f2bf(f0.x); t[1]=f2bf(f0.y); t[2]=f2bf(f0.z); t[3]=f2bf(f0.w);
        t[4]=f2bf(f1.x); t[5]=f2bf(f1.y); t[6]=f2bf(f1.z); t[7]=f2bf(f1.w);
        a[kk] = __builtin_bit_cast(bf16x8, t);
    }

    f32x4 acc[8];
#pragma unroll
    for (int nf = 0; nf < 8; ++nf) acc[nf] = (f32x4){0.f, 0.f, 0.f, 0.f};

#pragma unroll
    for (int kk = 0; kk < 8; ++kk) {
#pragma unroll
        for (int nf = 0; nf < 8; ++nf) {
            bf16x8 b = *(const bf16x8*)(WT + (size_t)(c + 16 * nf) * IN_DIM + kk * 32 + 8 * g);
            acc[nf] = MFMA16(a[kk], b, acc[nf]);
        }
    }

#pragma unroll
    for (int nf = 0; nf < 8; ++nf) {
        int col = c + 16 * nf;
        float bval = bias[col];
#pragma unroll
        for (int r = 0; r < 4; ++r) {
            int row = rowbase + 4 * g + r;
            short val = f2bf((acc[nf][r] + bval) * post_scale);
            if (transpose_out) Y[(size_t)col * N_TOK + row] = val;
            else               Y[(size_t)row * HID + col] = val;
        }
    }
}

// ------------------------- flash attention v4 ----------------------------
// 512 thr (8 waves); wave owns 32 q-rows; KVB=64 keys/tile; 32x32x16 MFMA.
__global__ __launch_bounds__(512, 2) void flash_kernel(
    const short* __restrict__ qh, const short* __restrict__ kh,
    const short* __restrict__ vhT,
    float* __restrict__ Opart, float* __restrict__ Mpart, float* __restrict__ Lpart,
    int nsplit)
{
    __shared__ short K_lds[2][KVB * HID];   // [buf][key*128+d]  2x16KB, swizzled
    __shared__ short V_lds[2][HID * KVB];   // [buf][d*64+key]   2x16KB, swizzled

    const int tid  = threadIdx.x;
    const int lane = tid & 63;
    const int wave = tid >> 6;
    const int hi   = lane >> 5;
    const int col  = lane & 31;

    // XCD-aware decode: all 32 blocks of an XCD share one KV split (L2-res.)
    const int lid = blockIdx.x;
    const int xcd = lid & 7, ib = lid >> 3;
    const int split = xcd % nsplit;
    const int qtile = ib + (8 * nsplit) * (xcd / nsplit);

    const int qb = qtile * BM + wave * 32;
    const int kvlen = N_TOK / nsplit;
    const int kv0 = split * kvlen;
    const int ntiles = kvlen / KVB;

    // Q B-frags: qf[kk] = qh[qb+col][16kk + 8hi + j]
    bf16x8 qf[8];
    const short* qrow = qh + (size_t)(qb + col) * HID + 8 * hi;
#pragma unroll
    for (int kk = 0; kk < 8; ++kk)
        qf[kk] = *(const bf16x8*)(qrow + 16 * kk);

    f32x16 o[4];
#pragma unroll
    for (int nf = 0; nf < 4; ++nf)
#pragma unroll
        for (int i = 0; i < 16; ++i) o[nf][i] = 0.f;
    float m_run = -1e30f, l_run = 0.f;   // log2 domain; l per half-lane

    // --- staging (pre-swizzled global source; LDS written linearly) ---
    const uint32_t L0 = (uint32_t)tid * 16;      // issue 0 byte
    const uint32_t L1 = L0 + 8192;               // issue 1 byte
    // K: row=L>>8 (256B rows), ch4=(L>>4)&15, src ch = ch4 ^ (row&7)
    const uint32_t kr0 = L0 >> 8, kc0 = ((L0 >> 4) & 15) ^ (kr0 & 7);
    const uint32_t kr1 = L1 >> 8, kc1 = ((L1 >> 4) & 15) ^ (kr1 & 7);
    // V: row d=L>>7 (128B rows), ch3=(L>>4)&7, src ch = ch3 ^ (d&7)
    const uint32_t vd0 = L0 >> 7, vc0 = ((L0 >> 4) & 7) ^ (vd0 & 7);
    const uint32_t vd1 = L1 >> 7, vc1 = ((L1 >> 4) & 7) ^ (vd1 & 7);
    const short* ks0 = kh + (size_t)(kv0 + kr0) * HID + kc0 * 8;
    const short* ks1 = kh + (size_t)(kv0 + kr1) * HID + kc1 * 8;
    const short* vs0 = vhT + (size_t)vd0 * N_TOK + kv0 + vc0 * 8;
    const short* vs1 = vhT + (size_t)vd1 * N_TOK + kv0 + vc1 * 8;

    auto stage = [&](int t, int buf) {
        gl16(ks0 + (size_t)t * (KVB * HID), &K_lds[buf][wave * 512]);
        gl16(ks1 + (size_t)t * (KVB * HID), &K_lds[buf][4096 + wave * 512]);
        gl16(vs0 + t * KVB, &V_lds[buf][wave * 512]);
        gl16(vs1 + t * KVB, &V_lds[buf][4096 + wave * 512]);
    };

    stage(0, 0);
    __syncthreads();

    for (int t = 0; t < ntiles; ++t) {
        const int cur = t & 1;
        if (t + 1 < ntiles) stage(t + 1, cur ^ 1);
        const short* Kc = &K_lds[cur][0];
        const short* Vc = &V_lds[cur][0];

        // ---- QK^T swapped: s0/s1 = S[key 0..31 / 32..63][q=col] ----
        f32x16 s0, s1;
#pragma unroll
        for (int i = 0; i < 16; ++i) { s0[i] = 0.f; s1[i] = 0.f; }
        __builtin_amdgcn_s_setprio(1);
#pragma unroll
        for (int kk = 0; kk < 8; ++kk) {
            const int sw = ((2 * kk + hi) ^ (col & 7)) << 3;
            bf16x8 ka0 = *(const bf16x8*)(Kc + col * HID + sw);
            bf16x8 ka1 = *(const bf16x8*)(Kc + (col + 32) * HID + sw);
            s0 = MFMA32(ka0, qf[kk], s0);
            s1 = MFMA32(ka1, qf[kk], s1);
        }
        __builtin_amdgcn_s_setprio(0);

        // ---- tile max: in-lane tree + cross-half shfl ----
        float pm = fmaxf(vmax16(s0), vmax16(s1));
        pm = fmaxf(pm, __shfl_xor(pm, 32, 64));
        if (!__all(pm - m_run <= 11.0f)) {          // defer-max (T13)
            float mn = fmaxf(m_run, pm);
            float cf = EXP2(m_run - mn);
            l_run *= cf;
#pragma unroll
            for (int nf = 0; nf < 4; ++nf)
#pragma unroll
                for (int i = 0; i < 16; ++i) o[nf][i] *= cf;
            m_run = mn;
        }

        // ---- exp + in-register P->bf16 A-frags ----
        // key of s-reg i: (i&3) + 8*(i>>2) + 4*hi. pa[ks] slot j <-> key
        // 16ks + 8hi + j; partner values fetched via shfl_xor(32).
        bf16x8 pa[4];
        float lacc = 0.f;
        auto process = [&](f32x16 sv, bf16x8& paA, bf16x8& paB) {
            float e[16];
#pragma unroll
            for (int i = 0; i < 16; ++i) e[i] = EXP2(sv[i] - m_run);
            lacc += (((e[0]+e[1])+(e[2]+e[3])) + ((e[4]+e[5])+(e[6]+e[7])))
                  + (((e[8]+e[9])+(e[10]+e[11])) + ((e[12]+e[13])+(e[14]+e[15])));
            uint32_t x0 = cvtpk(e[0], e[1]),   x1 = cvtpk(e[2], e[3]);
            uint32_t x2 = cvtpk(e[4], e[5]),   x3 = cvtpk(e[6], e[7]);
            uint32_t x4 = cvtpk(e[8], e[9]),   x5 = cvtpk(e[10], e[11]);
            uint32_t x6 = cvtpk(e[12], e[13]), x7 = cvtpk(e[14], e[15]);
            uint32_t p0 = xswap(x0), p1 = xswap(x1);
            uint32_t p2 = xswap(x2), p3 = xswap(x3);
            uint32_t p4 = xswap(x4), p5 = xswap(x5);
            uint32_t p6 = xswap(x6), p7 = xswap(x7);
            u32x4 wA, wB;
            wA[0] = hi ? p2 : x0;   // keys (0,1) | (8,9)
            wA[1] = hi ? p3 : x1;   // keys (2,3) | (10,11)
            wA[2] = hi ? x2 : p0;   // keys (4,5) | (12,13)
            wA[3] = hi ? x3 : p1;   // keys (6,7) | (14,15)
            wB[0] = hi ? p6 : x4;   // keys (16,17) | (24,25)
            wB[1] = hi ? p7 : x5;   // keys (18,19) | (26,27)
            wB[2] = hi ? x6 : p4;   // keys (20,21) | (28,29)
            wB[3] = hi ? x7 : p5;   // keys (22,23) | (30,31)
            paA = __builtin_bit_cast(bf16x8, wA);
            paB = __builtin_bit_cast(bf16x8, wB);
        };
        process(s0, pa[0], pa[1]);
        process(s1, pa[2], pa[3]);
        l_run += lacc;

        // ---- PV: O[q][d] += P[q][key] @ V[key][d] (B from V^T LDS) ----
        __builtin_amdgcn_s_setprio(1);
#pragma unroll
        for (int ks = 0; ks < 4; ++ks) {
            const int sw = ((2 * ks + hi) ^ (col & 7)) << 3;
#pragma unroll
            for (int nf = 0; nf < 4; ++nf) {
                bf16x8 vf = *(const bf16x8*)(Vc + (32 * nf + col) * KVB + sw);
                o[nf] = MFMA32(pa[ks], vf, o[nf]);
            }
        }
        __builtin_amdgcn_s_setprio(0);

        __syncthreads();   // all waves done reading cur; vmcnt drained
    }

    // ---- epilogue ----
    l_run += __shfl_xor(l_run, 32, 64);   // combine key-halves
    const size_t sbase = (size_t)split * N_TOK + qb;
#pragma unroll
    for (int nf = 0; nf < 4; ++nf)
#pragma unroll
        for (int r = 0; r < 16; ++r) {
            int qr = (r & 3) + 8 * (r >> 2) + 4 * hi;
            Opart[(sbase + qr) * HID + 32 * nf + col] = o[nf][r];
        }
    if (lane < 32) {
        Mpart[sbase + col] = m_run;
        Lpart[sbase + col] = l_run;
    }
}

// ------------------------- split combine ---------------------------------
__global__ void combine_kernel(const float* __restrict__ Opart,
                               const float* __restrict__ Mpart,
                               const float* __restrict__ Lpart,
                               short* __restrict__ O, int nsplit)
{
    int idx = blockIdx.x * 256 + threadIdx.x;
    int row = idx >> 5;
    int d4 = (idx & 31) << 2;
    if (row >= N_TOK) return;
    float M = -1e30f;
    for (int s = 0; s < nsplit; ++s) M = fmaxf(M, Mpart[(size_t)s * N_TOK + row]);
    float denom = 0.f, a0 = 0.f, a1 = 0.f, a2 = 0.f, a3 = 0.f;
    for (int s = 0; s < nsplit; ++s) {
        float w = EXP2(Mpart[(size_t)s * N_TOK + row] - M);   // log2 domain
        denom += w * Lpart[(size_t)s * N_TOK + row];
        float4 vv = *(const float4*)(Opart + ((size_t)s * N_TOK + row) * HID + d4);
        a0 += w * vv.x; a1 += w * vv.y; a2 += w * vv.z; a3 += w * vv.w;
    }
    float inv = 1.0f / denom;
    short4 ov;
    ov.x = f2bf(a0 * inv); ov.y = f2bf(a1 * inv);
    ov.z = f2bf(a2 * inv); ov.w = f2bf(a3 * inv);
    *(short4*)(O + (size_t)row * HID + d4) = ov;
}

// ------------------------- output projection -----------------------------
__global__ __launch_bounds__(256) void oproj_kernel(
    const short* __restrict__ O, const short* __restrict__ WoT,
    const float* __restrict__ bo, float* __restrict__ out)
{
    const int lane = threadIdx.x & 63;
    const int wave = threadIdx.x >> 6;
    const int g = lane >> 4, c = lane & 15;
    const int rowbase = blockIdx.x * 64 + wave * 16;

    bf16x8 a[4];
    const short* orow = O + (size_t)(rowbase + c) * HID;
#pragma unroll
    for (int kk = 0; kk < 4; ++kk)
        a[kk] = *(const bf16x8*)(orow + kk * 32 + 8 * g);

    f32x4 acc[16];
#pragma unroll
    for (int nf = 0; nf < 16; ++nf) acc[nf] = (f32x4){0.f, 0.f, 0.f, 0.f};

#pragma unroll
    for (int kk = 0; kk < 4; ++kk)
#pragma unroll
        for (int nf = 0; nf < 16; ++nf) {
            bf16x8 b = *(const bf16x8*)(WoT + (size_t)(c + 16 * nf) * HID + kk * 32 + 8 * g);
            acc[nf] = MFMA16(a[kk], b, acc[nf]);
        }

#pragma unroll
    for (int nf = 0; nf < 16; ++nf) {
        int col = c + 16 * nf;
        float bval = bo[col];
#pragma unroll
        for (int r = 0; r < 4; ++r)
            out[(size_t)(rowbase + 4 * g + r) * OUT_DIM + col] = acc[nf][r] + bval;
    }
}

// ------------------------- launch ----------------------------------------
extern "C" void kernel_launch(void* const* d_in, const int* in_sizes, int n_in,
                              void* d_out, int out_size, void* d_ws, size_t ws_size,
                              hipStream_t stream)
{
    (void)in_sizes; (void)n_in; (void)out_size;
    const float* q  = (const float*)d_in[0];
    const float* k  = (const float*)d_in[1];
    const float* v  = (const float*)d_in[2];
    const float* Wq = (const float*)d_in[3];
    const float* bq = (const float*)d_in[4];
    const float* Wk = (const float*)d_in[5];
    const float* bk = (const float*)d_in[6];
    const float* Wv = (const float*)d_in[7];
    const float* bvp= (const float*)d_in[8];
    const float* Wo = (const float*)d_in[9];
    const float* bo = (const float*)d_in[10];
    float* out = (float*)d_out;

    auto need = [](int ns) -> size_t {
        return (size_t)(512 * 1024)
             + (size_t)4 * N_TOK * HID * 2
             + (size_t)ns * N_TOK * HID * 4
             + (size_t)ns * N_TOK * 8
             + (size_t)256 * 1024;
    };
    int nsplit = 4;
    if (ws_size < need(4)) nsplit = 2;
    if (ws_size < need(2)) nsplit = 1;

    char* base = (char*)d_ws;
    size_t off = 0;
    auto alloc = [&](size_t bytes) -> void* {
        void* p = base + off;
        off = (off + bytes + 255) & ~(size_t)255;
        return p;
    };
    short* wtq = (short*)alloc(128 * 256 * 2);
    short* wtk = (short*)alloc(128 * 256 * 2);
    short* wtv = (short*)alloc(128 * 256 * 2);
    short* wto = (short*)alloc(256 * 128 * 2);
    short* qh  = (short*)alloc((size_t)N_TOK * HID * 2);
    short* khb = (short*)alloc((size_t)N_TOK * HID * 2);
    short* vhT = (short*)alloc((size_t)N_TOK * HID * 2);
    short* Ob  = (short*)alloc((size_t)N_TOK * HID * 2);
    float* Opart = (float*)alloc((size_t)nsplit * N_TOK * HID * 4);
    float* Mp  = (float*)alloc((size_t)nsplit * N_TOK * 4);
    float* Lp  = (float*)alloc((size_t)nsplit * N_TOK * 4);

    // 128^-0.5 * log2(e): logits land in log2 domain for exp2-based softmax
    const float SCALE_L2E = 0.088388347648318447f * 1.4426950408889634f;

    wt_kernel<<<128, 256, 0, stream>>>(Wq, wtq, 256, 128);
    wt_kernel<<<128, 256, 0, stream>>>(Wk, wtk, 256, 128);
    wt_kernel<<<128, 256, 0, stream>>>(Wv, wtv, 256, 128);
    wt_kernel<<<128, 256, 0, stream>>>(Wo, wto, 128, 256);

    proj_kernel<<<N_TOK / 64, 256, 0, stream>>>(q, wtq, bq, qh, SCALE_L2E, 0);
    proj_kernel<<<N_TOK / 64, 256, 0, stream>>>(k, wtk, bk, khb, 1.0f, 0);
    proj_kernel<<<N_TOK / 64, 256, 0, stream>>>(v, wtv, bvp, vhT, 1.0f, 1);

    flash_kernel<<<dim3((N_TOK / BM) * nsplit), 512, 0, stream>>>(
        qh, khb, vhT, Opart, Mp, Lp, nsplit);

    combine_kernel<<<(N_TOK * 32) / 256, 256, 0, stream>>>(Opart, Mp, Lp, Ob, nsplit);

    oproj_kernel<<<N_TOK / 64, 256, 0, stream>>>(Ob, wto, bo, out);
}